// Round 1
// baseline (518.383 us; speedup 1.0000x reference)
//
#include <hip/hip_runtime.h>
#include <cmath>
#include <cstdint>

#define NW      14
#define NST     (1 << NW)      // 16384 amplitudes
#define NLAYER  4
#define THREADS 1024

// Masks implementing the virtual (deferred) CNOT-ring permutation.
// Invariant: logical state Psi[x] = A[Q^{-1} x], Q = Lambda^k after k layers.
// Gate on logical wire w (bit p = 13-w): pairs {y, y^d}, d = Q^{-1} e_p;
// logical bit value of element at A[y] is parity(y & r), r = row_p(Q).
struct MaskTable {
    unsigned short d[NLAYER][NW];
    unsigned short r[NLAYER][NW];
    unsigned short meas;   // row_13(Q_final): sign bit for <Z_0>
};

__device__ __forceinline__ float2 cmul(float2 a, float2 b) {
    return make_float2(a.x * b.x - a.y * b.y, a.x * b.y + a.y * b.x);
}
// a*b + c (complex FMA)
__device__ __forceinline__ float2 cmadd(float2 a, float2 b, float2 c) {
    return make_float2(fmaf(a.x, b.x, fmaf(-a.y, b.y, c.x)),
                       fmaf(a.x, b.y, fmaf(a.y, b.x, c.y)));
}

__global__ __launch_bounds__(THREADS)
void vqc_kernel(const float* __restrict__ x_raw, const float* __restrict__ angles,
                float* __restrict__ out, MaskTable mt) {
    extern __shared__ float2 smem[];
    float2* A   = smem;                       // NST amplitudes
    float2* G   = smem + NST;                 // NLAYER*NW*4 fused 2x2 gates
    float*  red = (float*)(G + NLAYER * NW * 4);   // THREADS/64 partials

    const int b   = blockIdx.x;
    const int tid = threadIdx.x;

    // |0...0>
    for (int i = tid; i < NST; i += THREADS)
        A[i] = make_float2(i == 0 ? 1.f : 0.f, 0.f);

    // Build fused gate matrices: U = RZ(c) * RY(b) * RX(a)  [layer 0: * RY_enc(x)]
    if (tid < NLAYER * NW) {
        const int k = tid / NW, w = tid % NW;
        const float a  = angles[(k * NW + w) * 3 + 0];
        const float bb = angles[(k * NW + w) * 3 + 1];
        const float c  = angles[(k * NW + w) * 3 + 2];
        float sa, ca, sb, cb, sc, cc;
        sincosf(a * 0.5f, &sa, &ca);
        sincosf(bb * 0.5f, &sb, &cb);
        sincosf(c * 0.5f, &sc, &cc);
        // RY*RX
        float2 m00 = make_float2(cb * ca,  sb * sa);
        float2 m01 = make_float2(-sb * ca, -cb * sa);
        float2 m10 = make_float2(sb * ca,  -cb * sa);
        float2 m11 = make_float2(cb * ca,  -sb * sa);
        // RZ * (RY*RX): row0 *= e^{-ic/2}, row1 *= e^{+ic/2}
        const float2 e0 = make_float2(cc, -sc), e1 = make_float2(cc, sc);
        float2 u00 = cmul(e0, m00), u01 = cmul(e0, m01);
        float2 u10 = cmul(e1, m10), u11 = cmul(e1, m11);
        if (k == 0) {   // fuse per-sample encoding RY on the right
            const float xe = tanhf(x_raw[b * NW + w]) * 3.14159265358979f;
            float se, ce;
            sincosf(xe * 0.5f, &se, &ce);
            float2 v00 = make_float2(u00.x * ce + u01.x * se, u00.y * ce + u01.y * se);
            float2 v01 = make_float2(-u00.x * se + u01.x * ce, -u00.y * se + u01.y * ce);
            float2 v10 = make_float2(u10.x * ce + u11.x * se, u10.y * ce + u11.y * se);
            float2 v11 = make_float2(-u10.x * se + u11.x * ce, -u10.y * se + u11.y * ce);
            u00 = v00; u01 = v01; u10 = v10; u11 = v11;
        }
        const int gi = (k * NW + w) * 4;
        G[gi + 0] = u00; G[gi + 1] = u01; G[gi + 2] = u10; G[gi + 3] = u11;
    }
    __syncthreads();

    // 56 fused 1q gate passes; CNOT rings are virtual (index relabeling via mt).
    for (int k = 0; k < NLAYER; ++k) {
        for (int w = 0; w < NW; ++w) {
            const int gi = (k * NW + w) * 4;
            const float2 g00 = G[gi], g01 = G[gi + 1], g10 = G[gi + 2], g11 = G[gi + 3];
            const unsigned d  = mt.d[k][w];
            const unsigned r  = mt.r[k][w];
            const unsigned pb = 31 - __clz(d);      // pivot bit of pair direction
            const unsigned lo = (1u << pb) - 1u;
            #pragma unroll
            for (int jj = tid; jj < NST / 2; jj += THREADS) {
                const unsigned y  = ((jj & ~lo) << 1) | (jj & lo);  // bit pb == 0
                const unsigned y2 = y ^ d;
                const float2 u = A[y];
                const float2 v = A[y2];
                const bool s = __popc(y & r) & 1;   // logical bit of element at A[y]
                const float2 cuu = s ? g11 : g00;
                const float2 cuv = s ? g10 : g01;
                const float2 cvu = s ? g01 : g10;
                const float2 cvv = s ? g00 : g11;
                A[y]  = cmadd(cuv, v, cmul(cuu, u));
                A[y2] = cmadd(cvv, v, cmul(cvu, u));
            }
            __syncthreads();
        }
    }

    // <Z_0>: sign = parity(y & meas)
    float acc = 0.f;
    for (int i = tid; i < NST; i += THREADS) {
        const float2 vv = A[i];
        const float p = fmaf(vv.x, vv.x, vv.y * vv.y);
        acc += (__popc(i & (int)mt.meas) & 1) ? -p : p;
    }
    #pragma unroll
    for (int off = 32; off > 0; off >>= 1) acc += __shfl_down(acc, off);
    if ((tid & 63) == 0) red[tid >> 6] = acc;
    __syncthreads();
    if (tid == 0) {
        float s = 0.f;
        #pragma unroll
        for (int i = 0; i < THREADS / 64; ++i) s += red[i];
        out[b] = s;
    }
}

// ---------------- host-side GF(2) permutation algebra ----------------
struct GFM { unsigned short row[14]; };   // out bit i = parity(in & row[i])

static inline GFM gf_identity() {
    GFM m; for (int i = 0; i < 14; ++i) m.row[i] = (unsigned short)(1u << i); return m;
}
static inline GFM gf_mul(const GFM& A, const GFM& B) {   // C = A*B
    GFM C;
    for (int i = 0; i < 14; ++i) {
        unsigned rr = 0;
        for (int j = 0; j < 14; ++j)
            if ((A.row[i] >> j) & 1) rr ^= B.row[j];
        C.row[i] = (unsigned short)rr;
    }
    return C;
}

static void build_masks(MaskTable& mt) {
    // wire w <-> bit p = 13-w (wire 0 = MSB). CNOT(c,t): row_pt ^= row_pc.
    GFM Lam = gf_identity();
    for (int i = 0; i < 13; ++i) {            // CNOT(i, i+1), i = 0..12
        const int pc = 13 - i, pt = 13 - (i + 1);
        Lam.row[pt] ^= Lam.row[pc];
    }
    Lam.row[13] ^= Lam.row[0];                // CNOT(13, 0)

    GFM LamInv = gf_identity();               // inverse ring: reverse order
    LamInv.row[13] ^= LamInv.row[0];
    for (int i = 12; i >= 0; --i) {
        const int pc = 13 - i, pt = 13 - (i + 1);
        LamInv.row[pt] ^= LamInv.row[pc];
    }

    GFM Q = gf_identity(), Qinv = gf_identity();
    for (int k = 0; k < NLAYER; ++k) {
        for (int w = 0; w < NW; ++w) {
            const int p = 13 - w;
            unsigned dd = 0;
            for (int i = 0; i < 14; ++i)      // d = Qinv * e_p  (column p)
                dd |= ((unsigned)((Qinv.row[i] >> p) & 1)) << i;
            mt.d[k][w] = (unsigned short)dd;
            mt.r[k][w] = Q.row[p];
        }
        Q    = gf_mul(Lam, Q);                // Q_{k+1} = Lam * Q_k
        Qinv = gf_mul(Qinv, LamInv);          // Q_{k+1}^{-1} = Q_k^{-1} * Lam^{-1}
    }
    mt.meas = Q.row[13];                      // wire-0 bit of final index
}

extern "C" void kernel_launch(void* const* d_in, const int* in_sizes, int n_in,
                              void* d_out, int out_size, void* d_ws, size_t ws_size,
                              hipStream_t stream) {
    const float* x_raw  = (const float*)d_in[0];
    const float* angles = (const float*)d_in[1];
    float* out = (float*)d_out;
    const int bsz = in_sizes[0] / NW;

    MaskTable mt;
    build_masks(mt);

    const size_t lds = sizeof(float2) * (NST + NLAYER * NW * 4)
                     + sizeof(float) * (THREADS / 64);
    // gfx950 allows up to 160 KiB LDS per workgroup; request >64 KiB explicitly.
    (void)hipFuncSetAttribute((const void*)vqc_kernel,
                              hipFuncAttributeMaxDynamicSharedMemorySize, (int)lds);
    vqc_kernel<<<dim3(bsz), dim3(THREADS), lds, stream>>>(x_raw, angles, out, mt);
}

// Round 2
// 256.705 us; speedup vs baseline: 2.0194x; 2.0194x over previous
//
#include <hip/hip_runtime.h>
#include <cmath>
#include <cstdint>

#define NW      14
#define NST     (1 << NW)      // 16384 amplitudes
#define NLAYER  4
#define THREADS 1024
#define GTOT    (NLAYER * NW * 4)   // 224 float2 gate entries

// Virtual-CNOT bookkeeping: logical Psi[x] = A[Q^{-1}x], Q = Lambda^k.
// Gate on logical wire w (bit p=13-w): pairs along d = Q^{-1}e_p; logical bit
// of element at A[y] is parity(y & r), r = row_p(Q). Within one layer
// parity(d_i & r_j) = delta_ij, so 4 gates fuse into a clean 2^4 tensor block.
struct Grp4 { unsigned short d[4], r[4], lom[4], off[16]; };
struct Grp2 { unsigned short d[2], r[2], lom[2], off[4]; };
struct LayerPlan { Grp4 g4[3]; Grp2 g2; };
struct Plan { LayerPlan L[3]; unsigned short meas; };

__device__ __forceinline__ float2 cmul(float2 a, float2 b) {
    return make_float2(a.x * b.x - a.y * b.y, a.x * b.y + a.y * b.x);
}
__device__ __forceinline__ float2 cmadd(float2 a, float2 b, float2 c) {
    return make_float2(fmaf(a.x, b.x, fmaf(-a.y, b.y, c.x)),
                       fmaf(a.x, b.y, fmaf(a.y, b.x, c.y)));
}

__global__ __launch_bounds__(THREADS)
void vqc_kernel(const float* __restrict__ x_raw, const float* __restrict__ angles,
                float* __restrict__ out, Plan pl) {
    extern __shared__ float2 smem[];
    float2* A   = smem;                       // NST amplitudes
    float2* G   = smem + NST;                 // fused 2x2 gates, all layers
    float*  red = (float*)(G + GTOT);

    const int b   = blockIdx.x;
    const int tid = threadIdx.x;

    // ---- build fused gate matrices: U = RZ(c)*RY(b)*RX(a) [layer0: *RY_enc] ----
    if (tid < NLAYER * NW) {
        const int k = tid / NW, w = tid % NW;
        const float a  = angles[(k * NW + w) * 3 + 0];
        const float bb = angles[(k * NW + w) * 3 + 1];
        const float c  = angles[(k * NW + w) * 3 + 2];
        float sa, ca, sb, cb, sc, cc;
        sincosf(a * 0.5f, &sa, &ca);
        sincosf(bb * 0.5f, &sb, &cb);
        sincosf(c * 0.5f, &sc, &cc);
        float2 m00 = make_float2(cb * ca,  sb * sa);
        float2 m01 = make_float2(-sb * ca, -cb * sa);
        float2 m10 = make_float2(sb * ca,  -cb * sa);
        float2 m11 = make_float2(cb * ca,  -sb * sa);
        const float2 e0 = make_float2(cc, -sc), e1 = make_float2(cc, sc);
        float2 u00 = cmul(e0, m00), u01 = cmul(e0, m01);
        float2 u10 = cmul(e1, m10), u11 = cmul(e1, m11);
        if (k == 0) {   // fuse per-sample encoding RY on the right
            const float xe = tanhf(x_raw[b * NW + w]) * 3.14159265358979f;
            float se, ce;
            sincosf(xe * 0.5f, &se, &ce);
            float2 v00 = make_float2(u00.x * ce + u01.x * se, u00.y * ce + u01.y * se);
            float2 v01 = make_float2(-u00.x * se + u01.x * ce, -u00.y * se + u01.y * ce);
            float2 v10 = make_float2(u10.x * ce + u11.x * se, u10.y * ce + u11.y * se);
            float2 v11 = make_float2(-u10.x * se + u11.x * ce, -u10.y * se + u11.y * ce);
            u00 = v00; u01 = v01; u10 = v10; u11 = v11;
        }
        const int gi = (k * NW + w) * 4;
        G[gi + 0] = u00; G[gi + 1] = u01; G[gi + 2] = u10; G[gi + 3] = u11;
    }
    __syncthreads();

    // ---- init: |psi> after ALL layer-0 1q gates = product state (Q_0 = I) ----
    // amp(y) = prod_w U_w[bit_{13-w}(y), 0];  y = j*1024 + tid
    float2 common = make_float2(1.f, 0.f);
    #pragma unroll
    for (int bit = 0; bit < 10; ++bit) {
        const int w = 13 - bit;
        const float2 g0 = G[w * 4 + 0], g1 = G[w * 4 + 2];
        const float2 f = ((tid >> bit) & 1) ? g1 : g0;
        common = cmul(common, f);
    }
    float2 f0[2], f1[2], f2[2], f3[2];
    f0[0] = G[0 * 4 + 0]; f0[1] = G[0 * 4 + 2];
    f1[0] = G[1 * 4 + 0]; f1[1] = G[1 * 4 + 2];
    f2[0] = G[2 * 4 + 0]; f2[1] = G[2 * 4 + 2];
    f3[0] = G[3 * 4 + 0]; f3[1] = G[3 * 4 + 2];
    #pragma unroll
    for (int j = 0; j < 16; ++j) {
        const float2 o = cmul(cmul(f0[(j >> 3) & 1], f1[(j >> 2) & 1]),
                              cmul(f2[(j >> 1) & 1], f3[j & 1]));
        A[j * 1024 + tid] = cmul(common, o);
    }
    __syncthreads();

    // ---- layers 1..3: 3 x pass4 + 1 x pass2 each; rings stay virtual ----
    #pragma unroll
    for (int k = 0; k < 3; ++k) {
        #pragma unroll
        for (int g = 0; g < 3; ++g) {
            const Grp4& gr = pl.L[k].g4[g];
            const float2* Gk = G + ((k + 1) * NW + g * 4) * 4;
            unsigned y = tid;
            #pragma unroll
            for (int i = 0; i < 4; ++i) {          // deposit zeros at pivot bits
                const unsigned lo = gr.lom[i];
                y = ((y & ~lo) << 1) | (y & lo);
            }
            #pragma unroll
            for (int i = 0; i < 4; ++i)            // normalize coset base so slot a has labels a
                if (__popc(y & gr.r[i]) & 1) y ^= gr.d[i];
            float2 u[16];
            #pragma unroll
            for (int a = 0; a < 16; ++a) u[a] = A[y ^ gr.off[a]];
            #pragma unroll
            for (int i = 0; i < 4; ++i) {
                const float2 g00 = Gk[i * 4 + 0], g01 = Gk[i * 4 + 1];
                const float2 g10 = Gk[i * 4 + 2], g11 = Gk[i * 4 + 3];
                #pragma unroll
                for (int a = 0; a < 16; ++a) {
                    if (!(a & (1 << i))) {
                        const int a2 = a | (1 << i);
                        const float2 uu = u[a], vv = u[a2];
                        u[a]  = cmadd(g01, vv, cmul(g00, uu));
                        u[a2] = cmadd(g11, vv, cmul(g10, uu));
                    }
                }
            }
            #pragma unroll
            for (int a = 0; a < 16; ++a) A[y ^ gr.off[a]] = u[a];
            __syncthreads();
        }
        {   // wires 12,13
            const Grp2& gr = pl.L[k].g2;
            const float2* Gk = G + ((k + 1) * NW + 12) * 4;
            const float2 h00 = Gk[0], h01 = Gk[1], h10 = Gk[2], h11 = Gk[3];
            const float2 j00 = Gk[4], j01 = Gk[5], j10 = Gk[6], j11 = Gk[7];
            #pragma unroll
            for (int it = 0; it < 4; ++it) {
                unsigned y = tid + it * 1024;
                #pragma unroll
                for (int i = 0; i < 2; ++i) {
                    const unsigned lo = gr.lom[i];
                    y = ((y & ~lo) << 1) | (y & lo);
                }
                #pragma unroll
                for (int i = 0; i < 2; ++i)
                    if (__popc(y & gr.r[i]) & 1) y ^= gr.d[i];
                float2 u0 = A[y ^ gr.off[0]], u1 = A[y ^ gr.off[1]];
                float2 u2 = A[y ^ gr.off[2]], u3 = A[y ^ gr.off[3]];
                float2 t;
                t  = cmadd(h01, u1, cmul(h00, u0));
                u1 = cmadd(h11, u1, cmul(h10, u0)); u0 = t;
                t  = cmadd(h01, u3, cmul(h00, u2));
                u3 = cmadd(h11, u3, cmul(h10, u2)); u2 = t;
                t  = cmadd(j01, u2, cmul(j00, u0));
                u2 = cmadd(j11, u2, cmul(j10, u0)); u0 = t;
                t  = cmadd(j01, u3, cmul(j00, u1));
                u3 = cmadd(j11, u3, cmul(j10, u1)); u1 = t;
                A[y ^ gr.off[0]] = u0; A[y ^ gr.off[1]] = u1;
                A[y ^ gr.off[2]] = u2; A[y ^ gr.off[3]] = u3;
            }
            __syncthreads();
        }
    }

    // ---- <Z_0>: sign = parity(y & meas) ----
    float acc = 0.f;
    #pragma unroll
    for (int j = 0; j < 16; ++j) {
        const int i = j * 1024 + tid;
        const float2 vv = A[i];
        const float p = fmaf(vv.x, vv.x, vv.y * vv.y);
        acc += (__popc(i & (int)pl.meas) & 1) ? -p : p;
    }
    #pragma unroll
    for (int off = 32; off > 0; off >>= 1) acc += __shfl_down(acc, off);
    if ((tid & 63) == 0) red[tid >> 6] = acc;
    __syncthreads();
    if (tid == 0) {
        float s = 0.f;
        #pragma unroll
        for (int i = 0; i < THREADS / 64; ++i) s += red[i];
        out[b] = s;
    }
}

// ---------------- host-side GF(2) permutation algebra ----------------
struct GFM { unsigned short row[14]; };

static inline GFM gf_identity() {
    GFM m; for (int i = 0; i < 14; ++i) m.row[i] = (unsigned short)(1u << i); return m;
}
static inline GFM gf_mul(const GFM& A, const GFM& B) {
    GFM C;
    for (int i = 0; i < 14; ++i) {
        unsigned rr = 0;
        for (int j = 0; j < 14; ++j)
            if ((A.row[i] >> j) & 1) rr ^= B.row[j];
        C.row[i] = (unsigned short)rr;
    }
    return C;
}

static void reduce_pivots(const unsigned short* d, int n, unsigned short* lom) {
    unsigned short bas[14] = {0};
    int piv[4], np = 0;
    for (int i = 0; i < n; ++i) {
        unsigned v = d[i];
        while (v) {
            int m = 31 - __builtin_clz(v);
            if (bas[m]) v ^= bas[m];
            else { bas[m] = (unsigned short)v; piv[np++] = m; break; }
        }
    }
    for (int i = 0; i < np; ++i)            // sort ascending
        for (int j = i + 1; j < np; ++j)
            if (piv[j] < piv[i]) { int t = piv[i]; piv[i] = piv[j]; piv[j] = t; }
    for (int i = 0; i < n; ++i) lom[i] = (unsigned short)((1u << piv[i]) - 1);
}

static void build_group4(const GFM& Q, const GFM& Qinv, int w0, Grp4& g) {
    for (int i = 0; i < 4; ++i) {
        const int p = 13 - (w0 + i);
        unsigned dd = 0;
        for (int t = 0; t < 14; ++t) dd |= ((unsigned)((Qinv.row[t] >> p) & 1)) << t;
        g.d[i] = (unsigned short)dd;
        g.r[i] = Q.row[p];
    }
    reduce_pivots(g.d, 4, g.lom);
    for (int a = 0; a < 16; ++a) {
        unsigned o = 0;
        for (int i = 0; i < 4; ++i) if ((a >> i) & 1) o ^= g.d[i];
        g.off[a] = (unsigned short)o;
    }
}

static void build_group2(const GFM& Q, const GFM& Qinv, Grp2& g) {
    for (int i = 0; i < 2; ++i) {
        const int p = 13 - (12 + i);
        unsigned dd = 0;
        for (int t = 0; t < 14; ++t) dd |= ((unsigned)((Qinv.row[t] >> p) & 1)) << t;
        g.d[i] = (unsigned short)dd;
        g.r[i] = Q.row[p];
    }
    reduce_pivots(g.d, 2, g.lom);
    for (int a = 0; a < 4; ++a) {
        unsigned o = 0;
        for (int i = 0; i < 2; ++i) if ((a >> i) & 1) o ^= g.d[i];
        g.off[a] = (unsigned short)o;
    }
}

static void build_plan(Plan& pl) {
    GFM Lam = gf_identity();
    for (int i = 0; i < 13; ++i) {
        const int pc = 13 - i, pt = 13 - (i + 1);
        Lam.row[pt] ^= Lam.row[pc];
    }
    Lam.row[13] ^= Lam.row[0];

    GFM LamInv = gf_identity();
    LamInv.row[13] ^= LamInv.row[0];
    for (int i = 12; i >= 0; --i) {
        const int pc = 13 - i, pt = 13 - (i + 1);
        LamInv.row[pt] ^= LamInv.row[pc];
    }

    GFM Q = gf_identity(), Qinv = gf_identity();
    // layer 0's 1q gates are folded into the product-state init (Q_0 = I);
    // advance through ring 0:
    Q = gf_mul(Lam, Q); Qinv = gf_mul(Qinv, LamInv);
    for (int k = 0; k < 3; ++k) {
        for (int g = 0; g < 3; ++g) build_group4(Q, Qinv, g * 4, pl.L[k].g4[g]);
        build_group2(Q, Qinv, pl.L[k].g2);
        Q = gf_mul(Lam, Q); Qinv = gf_mul(Qinv, LamInv);
    }
    pl.meas = Q.row[13];
}

extern "C" void kernel_launch(void* const* d_in, const int* in_sizes, int n_in,
                              void* d_out, int out_size, void* d_ws, size_t ws_size,
                              hipStream_t stream) {
    const float* x_raw  = (const float*)d_in[0];
    const float* angles = (const float*)d_in[1];
    float* out = (float*)d_out;
    const int bsz = in_sizes[0] / NW;

    Plan pl;
    build_plan(pl);

    const size_t lds = sizeof(float2) * (NST + GTOT) + sizeof(float) * (THREADS / 64);
    (void)hipFuncSetAttribute((const void*)vqc_kernel,
                              hipFuncAttributeMaxDynamicSharedMemorySize, (int)lds);
    vqc_kernel<<<dim3(bsz), dim3(THREADS), lds, stream>>>(x_raw, angles, out, pl);
}

// Round 3
// 232.059 us; speedup vs baseline: 2.2338x; 1.1062x over previous
//
#include <hip/hip_runtime.h>
#include <cmath>
#include <cstdint>

#define NW       14
#define NST      (1 << NW)          // 16384 amplitudes
#define THREADS  1024
#define NLAYER   4
#define NPASS    12                 // layers 1..3 x 4 groups
#define WT_WORDS 512                // per-pass W-table: 256 complex = 512 words

typedef _Float16 f16x8 __attribute__((ext_vector_type(8)));
typedef float    f32x4 __attribute__((ext_vector_type(4)));

__device__ __forceinline__ float2 cmulf(float2 a, float2 b) {
    return make_float2(a.x * b.x - a.y * b.y, a.x * b.y + a.y * b.x);
}

// Storage: Re of logical x at word swz(x), Im at swz(x)+1 (float2-interleaved,
// XOR-swizzled so every pass's reads/writes hit the LDS bank floor).
__device__ __forceinline__ unsigned swz(unsigned x) {
    return (x << 1) ^ (((x >> 4) & 15u) << 1);
}
// CNOT ring as an index map: suffix-XOR over bits (wire j target of wire j-1),
// then CNOT(13,0) flips bit 13 by total parity.  x' = Lam * x over GF(2).
__device__ __forceinline__ unsigned ringp(unsigned x) {
    unsigned s = x;
    s ^= s >> 1; s ^= s >> 2; s ^= s >> 4; s ^= s >> 8;
    return s ^ ((s & 1u) << 13);
}

__global__ __launch_bounds__(THREADS)
void vqc_kernel(const float* __restrict__ x_raw, const float* __restrict__ angles,
                float* __restrict__ out) {
    extern __shared__ float smem[];
    float*  As = smem;                              // 2*NST words (128 KB)
    float*  Wt = As + 2 * NST;                      // NPASS*512 words (24 KB)
    float2* G  = (float2*)(Wt + NPASS * WT_WORDS);  // 224 fused 2x2 gates
    float*  red = (float*)(G + NLAYER * NW * 4);

    const int b   = blockIdx.x;
    const int tid = threadIdx.x;

    // ---- fused per-wire gates: U = RZ(c)*RY(b)*RX(a)  [layer0: *RY_enc(x)] ----
    if (tid < NLAYER * NW) {
        const int k = tid / NW, w = tid % NW;
        const float a  = angles[(k * NW + w) * 3 + 0];
        const float bb = angles[(k * NW + w) * 3 + 1];
        const float c  = angles[(k * NW + w) * 3 + 2];
        float sa, ca, sb, cb, sc, cc;
        sincosf(a * 0.5f, &sa, &ca);
        sincosf(bb * 0.5f, &sb, &cb);
        sincosf(c * 0.5f, &sc, &cc);
        float2 m00 = make_float2(cb * ca,  sb * sa);
        float2 m01 = make_float2(-sb * ca, -cb * sa);
        float2 m10 = make_float2(sb * ca,  -cb * sa);
        float2 m11 = make_float2(cb * ca,  -sb * sa);
        const float2 e0 = make_float2(cc, -sc), e1 = make_float2(cc, sc);
        float2 u00 = cmulf(e0, m00), u01 = cmulf(e0, m01);
        float2 u10 = cmulf(e1, m10), u11 = cmulf(e1, m11);
        if (k == 0) {
            const float xe = tanhf(x_raw[b * NW + w]) * 3.14159265358979f;
            float se, ce;
            sincosf(xe * 0.5f, &se, &ce);
            float2 v00 = make_float2(u00.x * ce + u01.x * se, u00.y * ce + u01.y * se);
            float2 v01 = make_float2(-u00.x * se + u01.x * ce, -u00.y * se + u01.y * ce);
            float2 v10 = make_float2(u10.x * ce + u11.x * se, u10.y * ce + u11.y * se);
            float2 v11 = make_float2(-u10.x * se + u11.x * ce, -u10.y * se + u11.y * ce);
            u00 = v00; u01 = v01; u10 = v10; u11 = v11;
        }
        const int gi = (k * NW + w) * 4;
        G[gi + 0] = u00; G[gi + 1] = u01; G[gi + 2] = u10; G[gi + 3] = u11;
    }
    __syncthreads();

    // ---- W tables: W = M0 (x) M1 (x) M2 (x) M3 per pass (16x16 complex) ----
    // Group g<3: wires g*4..g*4+3.  Group 3: I, I, U12, U13 (a = x[3:0]).
    #pragma unroll
    for (int i = 0; i < 3; ++i) {
        const int e  = tid + i * THREADS;           // 0..3071
        const int p  = e >> 8;
        const int ap = (e >> 4) & 15;               // row a'
        const int aa = e & 15;                      // col a
        const int k  = (p >> 2) + 1;
        const int g  = p & 3;
        float2 prod = make_float2(1.f, 0.f);
        #pragma unroll
        for (int i2 = 0; i2 < 4; ++i2) {
            const int bi = 3 - i2;                  // a-bit this factor acts on
            const int r_ = (ap >> bi) & 1, c_ = (aa >> bi) & 1;
            float2 f;
            if (g == 3 && i2 < 2) {
                f = make_float2((r_ == c_) ? 1.f : 0.f, 0.f);
            } else {
                const int w = (g < 3) ? (g * 4 + i2) : (12 + (i2 - 2));
                f = G[(k * NW + w) * 4 + r_ * 2 + c_];
            }
            prod = cmulf(prod, f);
        }
        // swizzled so A-fragment reads spread over banks
        const unsigned wofs = (unsigned)(p * WT_WORDS)
                            + (((((unsigned)ap << 4) | (unsigned)aa) << 1) ^ ((unsigned)ap << 1));
        Wt[wofs] = prod.x; Wt[wofs + 1] = prod.y;
    }

    // ---- init: product state after all layer-0 1q gates, written through ring ----
    {
        float2 common = make_float2(1.f, 0.f);
        #pragma unroll
        for (int bit = 0; bit < 10; ++bit) {
            const int w = 13 - bit;
            const float2 g0 = G[w * 4 + 0], g1 = G[w * 4 + 2];
            const float2 f = ((tid >> bit) & 1) ? g1 : g0;
            common = cmulf(common, f);
        }
        float2 f0[2], f1[2], f2[2], f3[2];
        f0[0] = G[0 * 4 + 0]; f0[1] = G[0 * 4 + 2];
        f1[0] = G[1 * 4 + 0]; f1[1] = G[1 * 4 + 2];
        f2[0] = G[2 * 4 + 0]; f2[1] = G[2 * 4 + 2];
        f3[0] = G[3 * 4 + 0]; f3[1] = G[3 * 4 + 2];
        #pragma unroll
        for (int j = 0; j < 16; ++j) {
            const float2 o = cmulf(cmulf(f0[(j >> 3) & 1], f1[(j >> 2) & 1]),
                                   cmulf(f2[(j >> 1) & 1], f3[j & 1]));
            const float2 amp = cmulf(common, o);
            const unsigned x = (unsigned)(j * 1024 + tid);
            *(float2*)&As[swz(ringp(x))] = amp;
        }
    }
    __syncthreads();

    // ---- 12 MFMA passes ----
    const int lane  = tid & 63;
    const int q     = lane >> 4;                    // quad
    const int m     = lane & 15;                    // A-row / B-col (coset-in-tile)
    const int ks    = (q & 1) * 8;                  // k-slice start within half
    const int imoff = q >> 1;                       // 0 = Re quads, 1 = Im quads
    const int wave  = tid >> 6;
    const f32x4 zerov = {0.f, 0.f, 0.f, 0.f};

    #pragma unroll 1
    for (int p = 0; p < NPASS; ++p) {
        const int g = p & 3;
        const int sh = (g < 3) ? (10 - 4 * g) : 0;  // group-bit position
        const unsigned lom = (1u << sh) - 1u;
        const bool ring = (g == 3);

        // A fragments: MFMA1 = [Wr | -Wi] (-> Out_re), MFMA2 = [Wi | Wr] (-> Out_im)
        f16x8 a1, a2;
        #pragma unroll
        for (int j = 0; j < 8; ++j) {
            const unsigned aa = (unsigned)(ks + j);
            const unsigned wofs = (unsigned)(p * WT_WORDS)
                                + (((((unsigned)m << 4) | aa) << 1) ^ ((unsigned)m << 1));
            const float re = Wt[wofs], im = Wt[wofs + 1];
            a1[j] = (_Float16)((q < 2) ? re : -im);
            a2[j] = (_Float16)((q < 2) ? im : re);
        }

        // read phase: B = [Sr; Si] for this wave's 4 tiles (16 cosets each)
        f16x8 bf[4];
        #pragma unroll
        for (int tt = 0; tt < 4; ++tt) {
            const unsigned c   = (unsigned)((wave * 4 + tt) * 16 + m);
            const unsigned chi = (c & ~lom) << 4, clo = c & lom;
            #pragma unroll
            for (int j = 0; j < 8; ++j) {
                const unsigned aa = (unsigned)(ks + j);
                const unsigned x  = chi | (aa << sh) | clo;
                bf[tt][j] = (_Float16)As[swz(x) + imoff];
            }
        }
        __syncthreads();    // all reads complete before any in-place/ring write

        // compute + write: D row = q*4+r (output label), col = m (coset)
        #pragma unroll
        for (int tt = 0; tt < 4; ++tt) {
            const f32x4 dre = __builtin_amdgcn_mfma_f32_16x16x32_f16(a1, bf[tt], zerov, 0, 0, 0);
            const f32x4 dim = __builtin_amdgcn_mfma_f32_16x16x32_f16(a2, bf[tt], zerov, 0, 0, 0);
            const unsigned c   = (unsigned)((wave * 4 + tt) * 16 + m);
            const unsigned chi = (c & ~lom) << 4, clo = c & lom;
            #pragma unroll
            for (int r = 0; r < 4; ++r) {
                const unsigned apr = (unsigned)(q * 4 + r);
                unsigned xo = chi | (apr << sh) | clo;
                if (ring) xo = ringp(xo);           // fold layer's CNOT ring into write
                *(float2*)&As[swz(xo)] = make_float2(dre[r], dim[r]);
            }
        }
        __syncthreads();
    }

    // ---- <Z_0>: state is canonical; sign = bit13 ----
    float acc = 0.f;
    #pragma unroll
    for (int j = 0; j < 16; ++j) {
        const unsigned x = (unsigned)(j * 1024 + tid);
        const float2 vv = *(const float2*)&As[swz(x)];
        const float pp = fmaf(vv.x, vv.x, vv.y * vv.y);
        acc += (j >= 8) ? -pp : pp;
    }
    #pragma unroll
    for (int off = 32; off > 0; off >>= 1) acc += __shfl_down(acc, off);
    if ((tid & 63) == 0) red[tid >> 6] = acc;
    __syncthreads();
    if (tid == 0) {
        float s = 0.f;
        #pragma unroll
        for (int i = 0; i < THREADS / 64; ++i) s += red[i];
        out[b] = s;
    }
}

extern "C" void kernel_launch(void* const* d_in, const int* in_sizes, int n_in,
                              void* d_out, int out_size, void* d_ws, size_t ws_size,
                              hipStream_t stream) {
    const float* x_raw  = (const float*)d_in[0];
    const float* angles = (const float*)d_in[1];
    float* out = (float*)d_out;
    const int bsz = in_sizes[0] / NW;

    const size_t lds = sizeof(float) * (2 * NST + NPASS * WT_WORDS)
                     + sizeof(float2) * (NLAYER * NW * 4)
                     + sizeof(float) * (THREADS / 64);
    (void)hipFuncSetAttribute((const void*)vqc_kernel,
                              hipFuncAttributeMaxDynamicSharedMemorySize, (int)lds);
    vqc_kernel<<<dim3(bsz), dim3(THREADS), lds, stream>>>(x_raw, angles, out);
}

// Round 4
// 147.746 us; speedup vs baseline: 3.5086x; 1.5707x over previous
//
#include <hip/hip_runtime.h>
#include <cmath>
#include <cstdint>

#define NW      14
#define NST     (1 << NW)       // 16384 amplitudes
#define THREADS 1024
#define NPASS   12              // layers 1..3 x 4 groups

typedef _Float16 f16;
typedef _Float16 f16x8 __attribute__((ext_vector_type(8)));
typedef float    f32x4 __attribute__((ext_vector_type(4)));
typedef unsigned short u16;

// Per-pass XOR-mask addressing: storage = phi_p(x) (GF(2) bijection).
// Mm[j] = phi(u_j)  (u_j = next pass's gate generators = c-in-tile dirs;
//                    ALSO the a'-placement for this pass's writes)
// Mt/Mw = phi(tile generators) — identical for read and write bases.
struct PassArg { u16 Mm[4]; u16 Mt[2]; u16 Mw[4]; };
struct Plan { PassArg ps[NPASS]; u16 initM[14]; u16 measR; u16 _pad; };

__device__ __forceinline__ float2 cmulf(float2 a, float2 b) {
    return make_float2(a.x * b.x - a.y * b.y, a.x * b.y + a.y * b.x);
}
// bank-spread hash: XORs unit bits [5:3] from high bits; keeps [2:0] runs intact
__device__ __forceinline__ unsigned swzu(unsigned s) {
    return s ^ ((((s >> 6) ^ (s >> 9) ^ (s >> 11)) & 7u) << 3);
}

__global__ __launch_bounds__(THREADS)
void vqc_kernel(const float* __restrict__ x_raw, const float* __restrict__ angles,
                float* __restrict__ out, Plan pl)
{
    extern __shared__ char smem[];
    f16*    Sh  = (f16*)smem;                    // Re plane [0,16384), Im [16384,32768)
    f16*    Bf  = Sh + 2 * NST;                  // 12*64*16 units: W B-fragments
    float2* G   = (float2*)(Bf + NPASS * 64 * 16);   // 4*14 fused 2x2 gates
    float*  red = (float*)(G + 4 * NW * 4);

    const int b   = blockIdx.x;
    const int tid = threadIdx.x;
    const int lane = tid & 63, wv = tid >> 6;
    const int q = lane >> 4, m = lane & 15;

    // ---- fused per-wire gates: U = RZ(c)*RY(b)*RX(a) [layer0: *RY_enc(x)] ----
    if (tid < 4 * NW) {
        const int k = tid / NW, w = tid % NW;
        const float a  = angles[(k * NW + w) * 3 + 0];
        const float bb = angles[(k * NW + w) * 3 + 1];
        const float c  = angles[(k * NW + w) * 3 + 2];
        float sa, ca, sb, cb, sc, cc;
        sincosf(a * 0.5f, &sa, &ca);
        sincosf(bb * 0.5f, &sb, &cb);
        sincosf(c * 0.5f, &sc, &cc);
        float2 m00 = make_float2(cb * ca,  sb * sa);
        float2 m01 = make_float2(-sb * ca, -cb * sa);
        float2 m10 = make_float2(sb * ca,  -cb * sa);
        float2 m11 = make_float2(cb * ca,  -sb * sa);
        const float2 e0 = make_float2(cc, -sc), e1 = make_float2(cc, sc);
        float2 u00 = cmulf(e0, m00), u01 = cmulf(e0, m01);
        float2 u10 = cmulf(e1, m10), u11 = cmulf(e1, m11);
        if (k == 0) {
            const float xe = tanhf(x_raw[b * NW + w]) * 3.14159265358979f;
            float se, ce;
            sincosf(xe * 0.5f, &se, &ce);
            float2 v00 = make_float2(u00.x * ce + u01.x * se, u00.y * ce + u01.y * se);
            float2 v01 = make_float2(-u00.x * se + u01.x * ce, -u00.y * se + u01.y * ce);
            float2 v10 = make_float2(u10.x * ce + u11.x * se, u10.y * ce + u11.y * se);
            float2 v11 = make_float2(-u10.x * se + u11.x * ce, -u10.y * se + u11.y * ce);
            u00 = v00; u01 = v01; u10 = v10; u11 = v11;
        }
        const int gi = (k * NW + w) * 4;
        G[gi + 0] = u00; G[gi + 1] = u01; G[gi + 2] = u10; G[gi + 3] = u11;
    }
    __syncthreads();

    // ---- W B-fragments (per pass, 16x16 complex as 2 real MFMA B-operands) ----
    // B1 = [Wr'; -Wi'], B2 = [Wi'; Wr'], Wx'[a,a'] = Wx[a'][a]; lane (q,m): col=m=a',
    // k=q*8+j2 (k<16: Re-rows a=k, k>=16: Im-rows a=k-16).
    if (tid < NPASS * 64) {
        const int p = tid >> 6, l6 = tid & 63;
        const int bq = l6 >> 4, bm = l6 & 15;
        const int layer = (p >> 2) + 1, g = p & 3;
        const int gbt[4][4] = {{10,11,12,13},{6,7,8,9},{2,3,4,5},{0,1,6,7}};
        float2 F[4][4];
        #pragma unroll
        for (int j = 0; j < 4; ++j) {
            if (g == 3 && j >= 2) {   // pad wires (bits 6,7): identity
                F[j][0] = make_float2(1.f,0.f); F[j][1] = make_float2(0.f,0.f);
                F[j][2] = make_float2(0.f,0.f); F[j][3] = make_float2(1.f,0.f);
            } else {
                const int wire = 13 - gbt[g][j];
                const float2* Gp = G + (layer * NW + wire) * 4;
                F[j][0]=Gp[0]; F[j][1]=Gp[1]; F[j][2]=Gp[2]; F[j][3]=Gp[3];
            }
        }
        const int a3 = bq & 1, half = bq >> 1;
        const float2 p3 = F[3][((bm >> 3) & 1) * 2 + a3];
        const int basei = (p * 64 + l6) * 16;
        #pragma unroll
        for (int j2 = 0; j2 < 8; ++j2) {
            float2 v = cmulf(p3, F[2][((bm >> 2) & 1) * 2 + ((j2 >> 2) & 1)]);
            v = cmulf(v, F[1][((bm >> 1) & 1) * 2 + ((j2 >> 1) & 1)]);
            v = cmulf(v, F[0][((bm >> 0) & 1) * 2 + (j2 & 1)]);
            Bf[basei + j2]     = (f16)(half ? -v.y : v.x);
            Bf[basei + 8 + j2] = (f16)(half ?  v.x : v.y);
        }
    }

    // ---- init: product state after all layer-0 1q gates, placed via initM ----
    {
        float2 common = make_float2(1.f, 0.f);
        #pragma unroll
        for (int bit = 0; bit < 10; ++bit) {
            const int w = 13 - bit;
            const float2 f = ((tid >> bit) & 1) ? G[w * 4 + 2] : G[w * 4 + 0];
            common = cmulf(common, f);
        }
        unsigned p10 = 0;
        #pragma unroll
        for (int bit = 0; bit < 10; ++bit)
            p10 ^= ((tid >> bit) & 1) ? (unsigned)pl.initM[bit] : 0u;
        float2 f0[2], f1[2], f2[2], f3[2];
        f0[0] = G[0*4+0]; f0[1] = G[0*4+2];
        f1[0] = G[1*4+0]; f1[1] = G[1*4+2];
        f2[0] = G[2*4+0]; f2[1] = G[2*4+2];
        f3[0] = G[3*4+0]; f3[1] = G[3*4+2];
        #pragma unroll
        for (int j = 0; j < 16; ++j) {
            const float2 o = cmulf(cmulf(f0[(j >> 3) & 1], f1[(j >> 2) & 1]),
                                   cmulf(f2[(j >> 1) & 1], f3[j & 1]));
            const float2 amp = cmulf(common, o);
            const unsigned sj = ((j & 1) ? pl.initM[10] : 0) ^ ((j & 2) ? pl.initM[11] : 0)
                              ^ ((j & 4) ? pl.initM[12] : 0) ^ ((j & 8) ? pl.initM[13] : 0);
            const unsigned ph = swzu(p10 ^ sj);
            Sh[ph]       = (f16)amp.x;
            Sh[ph + NST] = (f16)amp.y;
        }
    }
    __syncthreads();

    // ---- 12 MFMA passes: state = A operand, W = B operand ----
    const unsigned plane_off = (unsigned)(q >> 1) << 14;
    #pragma unroll
    for (int p = 0; p < NPASS; ++p) {
        const PassArg& P = pl.ps[p];
        const unsigned pm = ((m & 1) ? P.Mm[0] : 0) ^ ((m & 2) ? P.Mm[1] : 0)
                          ^ ((m & 4) ? P.Mm[2] : 0) ^ ((m & 8) ? P.Mm[3] : 0);
        const unsigned wb = ((wv & 1) ? P.Mw[0] : 0) ^ ((wv & 2) ? P.Mw[1] : 0)
                          ^ ((wv & 4) ? P.Mw[2] : 0) ^ ((wv & 8) ? P.Mw[3] : 0);
        const unsigned b0 = pm ^ wb;
        const f16x8 bf1 = *(const f16x8*)(Bf + (p * 64 + lane) * 16);
        const f16x8 bf2 = *(const f16x8*)(Bf + (p * 64 + lane) * 16 + 8);
        unsigned swt[4];
        f16x8 av[4];
        #pragma unroll
        for (int tt = 0; tt < 4; ++tt) {
            const unsigned s0 = b0 ^ ((tt & 1) ? P.Mt[0] : 0) ^ ((tt & 2) ? P.Mt[1] : 0);
            const unsigned sw = swzu(s0);
            swt[tt] = sw;
            av[tt] = *(const f16x8*)(Sh + plane_off + (sw ^ ((unsigned)(q & 1) << 3)));
        }
        __syncthreads();   // all reads done before in-place re-layout writes
        const f32x4 z4 = {0.f, 0.f, 0.f, 0.f};
        #pragma unroll
        for (int tt = 0; tt < 4; ++tt) {
            const f32x4 d1 = __builtin_amdgcn_mfma_f32_16x16x32_f16(av[tt], bf1, z4, 0, 0, 0);
            const f32x4 d2 = __builtin_amdgcn_mfma_f32_16x16x32_f16(av[tt], bf2, z4, 0, 0, 0);
            union { f16 h[4]; uint2 u; } c1, c2;
            #pragma unroll
            for (int r = 0; r < 4; ++r) { c1.h[r] = (f16)d1[r]; c2.h[r] = (f16)d2[r]; }
            const unsigned wu = swt[tt] ^ ((unsigned)q << 2);
            *(uint2*)(Sh + wu)       = c1.u;   // Re plane, b64
            *(uint2*)(Sh + NST + wu) = c2.u;   // Im plane, b64
        }
        __syncthreads();
    }

    // ---- <Z_0>: sign = parity(s & measR) over storage index s ----
    float acc = 0.f;
    {
        const unsigned base = (unsigned)tid * 16;
        const unsigned swb  = swzu(base);
        const f16x8 r0 = *(const f16x8*)(Sh + swb);
        const f16x8 r1 = *(const f16x8*)(Sh + (swb ^ 8u));
        const f16x8 i0 = *(const f16x8*)(Sh + NST + swb);
        const f16x8 i1 = *(const f16x8*)(Sh + NST + (swb ^ 8u));
        const int pb = __popc(base & (unsigned)pl.measR) & 1;
        #pragma unroll
        for (int e = 0; e < 8; ++e) {
            float re = (float)r0[e], im = (float)i0[e];
            float pw = fmaf(re, re, im * im);
            acc += (pb ^ (__popc((unsigned)e & (unsigned)pl.measR) & 1)) ? -pw : pw;
            re = (float)r1[e]; im = (float)i1[e];
            pw = fmaf(re, re, im * im);
            acc += (pb ^ (__popc((unsigned)(e + 8) & (unsigned)pl.measR) & 1)) ? -pw : pw;
        }
    }
    #pragma unroll
    for (int off = 32; off > 0; off >>= 1) acc += __shfl_down(acc, off);
    if ((tid & 63) == 0) red[tid >> 6] = acc;
    __syncthreads();
    if (tid == 0) {
        float s = 0.f;
        #pragma unroll
        for (int i = 0; i < THREADS / 64; ++i) s += red[i];
        out[b] = s;
    }
}

// ---------------- host-side GF(2) layout scheduling ----------------
struct GFm { u16 col[14]; };   // col[b] = image of e_b

static unsigned ringp_host(unsigned x) {
    unsigned s = x;
    s ^= s >> 1; s ^= s >> 2; s ^= s >> 4; s ^= s >> 8;
    s &= 0x3FFFu;
    return (s ^ ((s & 1u) << 13)) & 0x3FFFu;
}
static u16 gf_apply(const GFm& m, u16 v) {
    u16 r = 0;
    for (int b = 0; b < 14; ++b) if ((v >> b) & 1) r ^= m.col[b];
    return r;
}
static GFm gf_compose(const GFm& A, const GFm& B) {   // A∘B
    GFm C;
    for (int b = 0; b < 14; ++b) C.col[b] = gf_apply(A, B.col[b]);
    return C;
}
static void rows_from(const GFm& A, u16 r[14]) {
    for (int i = 0; i < 14; ++i) {
        u16 mm = 0;
        for (int b = 0; b < 14; ++b) mm |= (u16)(((A.col[b] >> i) & 1) << b);
        r[i] = mm;
    }
}
static GFm from_rows(const u16 r[14]) {
    GFm A;
    for (int b = 0; b < 14; ++b) {
        u16 c = 0;
        for (int i = 0; i < 14; ++i) c |= (u16)(((r[i] >> b) & 1) << i);
        A.col[b] = c;
    }
    return A;
}
static GFm gf_inv(const GFm& A) {
    u16 M[14], I[14];
    rows_from(A, M);
    for (int i = 0; i < 14; ++i) I[i] = (u16)(1u << i);
    for (int c = 0; c < 14; ++c) {
        int p = c;
        while (p < 14 && !((M[p] >> c) & 1)) ++p;
        if (p == 14) continue;   // shouldn't happen (invertible)
        u16 t = M[c]; M[c] = M[p]; M[p] = t;
        t = I[c]; I[c] = I[p]; I[p] = t;
        for (int r2 = 0; r2 < 14; ++r2)
            if (r2 != c && ((M[r2] >> c) & 1)) { M[r2] ^= M[c]; I[r2] ^= I[c]; }
    }
    return from_rows(I);
}

static void build_plan(Plan& pl) {
    GFm ring, ringInv;
    for (int b = 0; b < 14; ++b) ring.col[b] = (u16)ringp_host(1u << b);
    ringInv = gf_inv(ring);

    // phi0: G0 bits {10..13}->slots[0..3]; G1 {6..9}->[4..7]; G2 {2..5}->[8..11]; b0->12, b1->13
    GFm phi;
    for (int j = 0; j < 4; ++j) phi.col[10 + j] = (u16)(1u << j);
    for (int j = 0; j < 4; ++j) phi.col[6 + j]  = (u16)(1u << (4 + j));
    for (int j = 0; j < 4; ++j) phi.col[2 + j]  = (u16)(1u << (8 + j));
    phi.col[0] = (u16)(1u << 12);
    phi.col[1] = (u16)(1u << 13);

    // init: storage = phi0(lambda(x))  (layer-0 ring folded into init placement)
    for (int b = 0; b < 14; ++b) pl.initM[b] = gf_apply(phi, ring.col[b]);

    const int gb[4][4] = {{10,11,12,13},{6,7,8,9},{2,3,4,5},{0,1,6,7}};

    for (int p = 0; p < NPASS; ++p) {
        const int g = p & 3;
        // u_j: next pass's gate generators in current frame (ring-crossing for g==3)
        u16 uv[4];
        if (g < 3) for (int j = 0; j < 4; ++j) uv[j] = (u16)(1u << gb[g + 1][j]);
        else       for (int j = 0; j < 4; ++j) uv[j] = ringInv.col[10 + j];
        for (int j = 0; j < 4; ++j) pl.ps[p].Mm[j] = gf_apply(phi, uv[j]);

        // complete basis {e_gp, u} with unit vectors t[0..5]
        u16 span[14]; int ns = 0;
        u16 tv[6]; int nt = 0;
        auto tryAdd = [&](u16 v) -> bool {
            bool ch = true;
            while (ch) {
                ch = false;
                for (int i = 0; i < ns; ++i) {
                    const int tb = 31 - __builtin_clz((unsigned)span[i]);
                    if ((v >> tb) & 1) { v ^= span[i]; ch = true; }
                }
            }
            if (!v) return false;
            span[ns++] = v;
            return true;
        };
        for (int j = 0; j < 4; ++j) tryAdd((u16)(1u << gb[g][j]));
        for (int j = 0; j < 4; ++j) tryAdd(uv[j]);
        for (int b2 = 0; b2 < 14 && nt < 6; ++b2)
            if (tryAdd((u16)(1u << b2))) tv[nt++] = (u16)(1u << b2);
        for (int i = 0; i < 2; ++i) pl.ps[p].Mt[i] = gf_apply(phi, tv[i]);
        for (int i = 0; i < 4; ++i) pl.ps[p].Mw[i] = gf_apply(phi, tv[i + 2]);

        // transition: phi'(u_j)=2^j, phi'(e_gp_j)=phi(u_j), phi'(t)=phi(t)
        GFm Bm;
        for (int j = 0; j < 4; ++j) Bm.col[j]     = (u16)(1u << gb[g][j]);
        for (int j = 0; j < 4; ++j) Bm.col[4 + j] = uv[j];
        for (int i = 0; i < 6; ++i) Bm.col[8 + i] = tv[i];
        GFm Binv = gf_inv(Bm);
        u16 img[14];
        for (int j = 0; j < 4; ++j) img[j]     = pl.ps[p].Mm[j];
        for (int j = 0; j < 4; ++j) img[4 + j] = (u16)(1u << j);
        for (int i = 0; i < 6; ++i) img[8 + i] = gf_apply(phi, tv[i]);
        GFm nphi;
        for (int b2 = 0; b2 < 14; ++b2) {
            const u16 coef = gf_apply(Binv, (u16)(1u << b2));
            u16 v = 0;
            for (int j = 0; j < 14; ++j) if ((coef >> j) & 1) v ^= img[j];
            nphi.col[b2] = v;
        }
        if (g == 3) nphi = gf_compose(nphi, ringInv);   // fold layer's CNOT ring
        phi = nphi;
    }

    GFm pinv = gf_inv(phi);
    u16 rows[14];
    rows_from(pinv, rows);
    pl.measR = rows[13];   // parity mask: logical bit13 (wire 0) from storage index
    pl._pad = 0;
}

extern "C" void kernel_launch(void* const* d_in, const int* in_sizes, int n_in,
                              void* d_out, int out_size, void* d_ws, size_t ws_size,
                              hipStream_t stream) {
    const float* x_raw  = (const float*)d_in[0];
    const float* angles = (const float*)d_in[1];
    float* out = (float*)d_out;
    const int bsz = in_sizes[0] / NW;

    Plan pl;
    build_plan(pl);

    const size_t lds = (size_t)2 * NST * sizeof(f16)          // state planes
                     + (size_t)NPASS * 64 * 16 * sizeof(f16)  // W B-fragments
                     + (size_t)4 * NW * 4 * sizeof(float2)    // fused gates
                     + (size_t)(THREADS / 64) * sizeof(float);
    (void)hipFuncSetAttribute((const void*)vqc_kernel,
                              hipFuncAttributeMaxDynamicSharedMemorySize, (int)lds);
    vqc_kernel<<<dim3(bsz), dim3(THREADS), lds, stream>>>(x_raw, angles, out, pl);
}

// Round 5
// 126.932 us; speedup vs baseline: 4.0839x; 1.1640x over previous
//
#include <hip/hip_runtime.h>
#include <cmath>
#include <cstdint>

#define NW      14
#define NST     (1 << NW)       // 16384 amplitudes
#define THREADS 1024
#define NPASS   12              // layers 1..3 x 4 groups

typedef _Float16 f16;
typedef _Float16 f16x8 __attribute__((ext_vector_type(8)));
typedef float    f32x4 __attribute__((ext_vector_type(4)));
typedef unsigned short u16;

// Per-pass XOR-mask addressing: storage = phi_p(x) (GF(2) bijection).
// Mm[j] = phi(u_j)  (u_j = next pass's gate generators = c-in-tile dirs;
//                    ALSO the a'-placement for this pass's writes)
// Mt/Mw = phi(tile generators) — identical for read and write bases.
struct PassArg { u16 Mm[4]; u16 Mt[2]; u16 Mw[4]; };
struct Plan { PassArg ps[NPASS]; u16 initM[14]; u16 measR; u16 _pad; };

__device__ __forceinline__ float2 cmulf(float2 a, float2 b) {
    return make_float2(a.x * b.x - a.y * b.y, a.x * b.y + a.y * b.x);
}
// bank-spread hash: XORs unit bits [5:3] from high bits; keeps [2:0] runs intact
__device__ __forceinline__ unsigned swzu(unsigned s) {
    return s ^ ((((s >> 6) ^ (s >> 9) ^ (s >> 11)) & 7u) << 3);
}

__global__ __launch_bounds__(THREADS)
void vqc_kernel(const float* __restrict__ x_raw, const float* __restrict__ angles,
                float* __restrict__ out, Plan pl)
{
    extern __shared__ char smem[];
    f16*    Sh  = (f16*)smem;                    // buf0: Re [0,16K), Im [16K,32K); buf1: [32K,64K)
    f16*    Bf  = Sh + 4 * NST;                  // 12*64*16 units: W B-fragments
    float2* G   = (float2*)(Bf + NPASS * 64 * 16);   // 4*14 fused 2x2 gates
    float*  red = (float*)(G + 4 * NW * 4);

    const int b   = blockIdx.x;
    const int tid = threadIdx.x;
    const int lane = tid & 63, wv = tid >> 6;
    const int q = lane >> 4, m = lane & 15;

    // ---- fused per-wire gates: U = RZ(c)*RY(b)*RX(a) [layer0: *RY_enc(x)] ----
    if (tid < 4 * NW) {
        const int k = tid / NW, w = tid % NW;
        const float a  = angles[(k * NW + w) * 3 + 0];
        const float bb = angles[(k * NW + w) * 3 + 1];
        const float c  = angles[(k * NW + w) * 3 + 2];
        float sa, ca, sb, cb, sc, cc;
        sincosf(a * 0.5f, &sa, &ca);
        sincosf(bb * 0.5f, &sb, &cb);
        sincosf(c * 0.5f, &sc, &cc);
        float2 m00 = make_float2(cb * ca,  sb * sa);
        float2 m01 = make_float2(-sb * ca, -cb * sa);
        float2 m10 = make_float2(sb * ca,  -cb * sa);
        float2 m11 = make_float2(cb * ca,  -sb * sa);
        const float2 e0 = make_float2(cc, -sc), e1 = make_float2(cc, sc);
        float2 u00 = cmulf(e0, m00), u01 = cmulf(e0, m01);
        float2 u10 = cmulf(e1, m10), u11 = cmulf(e1, m11);
        if (k == 0) {
            const float xe = tanhf(x_raw[b * NW + w]) * 3.14159265358979f;
            float se, ce;
            sincosf(xe * 0.5f, &se, &ce);
            float2 v00 = make_float2(u00.x * ce + u01.x * se, u00.y * ce + u01.y * se);
            float2 v01 = make_float2(-u00.x * se + u01.x * ce, -u00.y * se + u01.y * ce);
            float2 v10 = make_float2(u10.x * ce + u11.x * se, u10.y * ce + u11.y * se);
            float2 v11 = make_float2(-u10.x * se + u11.x * ce, -u10.y * se + u11.y * ce);
            u00 = v00; u01 = v01; u10 = v10; u11 = v11;
        }
        const int gi = (k * NW + w) * 4;
        G[gi + 0] = u00; G[gi + 1] = u01; G[gi + 2] = u10; G[gi + 3] = u11;
    }
    __syncthreads();

    // ---- W B-fragments (per pass, 16x16 complex as 2 real MFMA B-operands) ----
    // Factor j acts on a-bit j; entry [r,c]: r = (bm>>j)&1, c = (a>>j)&1.
    // Group g<3: bitpos = 10-4g+j (wire 13-bitpos). Group 3: j<2 real (wires 13,12),
    // j>=2 identity.  NO private arrays: gate entries read straight from LDS G.
    if (tid < NPASS * 64) {
        const int p = tid >> 6, l6 = tid & 63;
        const int bq = l6 >> 4, bm = l6 & 15;
        const int layer = (p >> 2) + 1, g = p & 3;
        const int a3 = bq & 1, half = bq >> 1;

        // factor 3 (row & col fixed per thread)
        float2 p3;
        if (g == 3) {
            const int r3 = (bm >> 3) & 1;
            p3 = make_float2((r3 == a3) ? 1.f : 0.f, 0.f);
        } else {
            const int wire = 13 - (10 - 4 * g + 3);
            p3 = G[(layer * NW + wire) * 4 + ((bm >> 3) & 1) * 2 + a3];
        }
        // factors 0..2: row fixed, both columns preloaded into registers
        float2 e0a, e0b, e1a, e1b, e2a, e2b;
        {
            const int r0 = bm & 1, r1 = (bm >> 1) & 1, r2 = (bm >> 2) & 1;
            if (g == 3) {
                const float2* G13 = G + (layer * NW + 13) * 4;   // factor 0
                const float2* G12 = G + (layer * NW + 12) * 4;   // factor 1
                e0a = G13[r0 * 2 + 0]; e0b = G13[r0 * 2 + 1];
                e1a = G12[r1 * 2 + 0]; e1b = G12[r1 * 2 + 1];
                e2a = make_float2(r2 == 0 ? 1.f : 0.f, 0.f);     // identity
                e2b = make_float2(r2 == 1 ? 1.f : 0.f, 0.f);
            } else {
                const float2* G0 = G + (layer * NW + (13 - (10 - 4 * g + 0))) * 4;
                const float2* G1 = G + (layer * NW + (13 - (10 - 4 * g + 1))) * 4;
                const float2* G2 = G + (layer * NW + (13 - (10 - 4 * g + 2))) * 4;
                e0a = G0[r0 * 2 + 0]; e0b = G0[r0 * 2 + 1];
                e1a = G1[r1 * 2 + 0]; e1b = G1[r1 * 2 + 1];
                e2a = G2[r2 * 2 + 0]; e2b = G2[r2 * 2 + 1];
            }
        }
        const int basei = (p * 64 + l6) * 16;
        #pragma unroll
        for (int j2 = 0; j2 < 8; ++j2) {
            float2 v = cmulf(p3, (j2 & 4) ? e2b : e2a);
            v = cmulf(v, (j2 & 2) ? e1b : e1a);
            v = cmulf(v, (j2 & 1) ? e0b : e0a);
            Bf[basei + j2]     = (f16)(half ? -v.y : v.x);
            Bf[basei + 8 + j2] = (f16)(half ?  v.x : v.y);
        }
    }

    // ---- init: product state after all layer-0 1q gates, placed via initM (buf0) ----
    {
        float2 common = make_float2(1.f, 0.f);
        #pragma unroll
        for (int bit = 0; bit < 10; ++bit) {
            const int w = 13 - bit;
            const float2 f = ((tid >> bit) & 1) ? G[w * 4 + 2] : G[w * 4 + 0];
            common = cmulf(common, f);
        }
        unsigned p10 = 0;
        #pragma unroll
        for (int bit = 0; bit < 10; ++bit)
            p10 ^= ((tid >> bit) & 1) ? (unsigned)pl.initM[bit] : 0u;
        float2 f0[2], f1[2], f2[2], f3[2];
        f0[0] = G[0*4+0]; f0[1] = G[0*4+2];
        f1[0] = G[1*4+0]; f1[1] = G[1*4+2];
        f2[0] = G[2*4+0]; f2[1] = G[2*4+2];
        f3[0] = G[3*4+0]; f3[1] = G[3*4+2];
        #pragma unroll
        for (int j = 0; j < 16; ++j) {
            const float2 o = cmulf(cmulf(f0[(j >> 3) & 1], f1[(j >> 2) & 1]),
                                   cmulf(f2[(j >> 1) & 1], f3[j & 1]));
            const float2 amp = cmulf(common, o);
            const unsigned sj = ((j & 1) ? pl.initM[10] : 0) ^ ((j & 2) ? pl.initM[11] : 0)
                              ^ ((j & 4) ? pl.initM[12] : 0) ^ ((j & 8) ? pl.initM[13] : 0);
            const unsigned ph = swzu(p10 ^ sj);
            Sh[ph]       = (f16)amp.x;
            Sh[ph + NST] = (f16)amp.y;
        }
    }
    __syncthreads();

    // ---- 12 MFMA passes, ping-pong buffers, ONE barrier per pass ----
    const unsigned plane_off = (unsigned)(q >> 1) << 14;
    const f32x4 z4 = {0.f, 0.f, 0.f, 0.f};
    #pragma unroll
    for (int p = 0; p < NPASS; ++p) {
        const f16* S = Sh + ((p & 1) ? 2 * NST : 0);
        f16*       D = Sh + ((p & 1) ? 0 : 2 * NST);
        const PassArg& P = pl.ps[p];
        const unsigned pm = ((m & 1) ? P.Mm[0] : 0) ^ ((m & 2) ? P.Mm[1] : 0)
                          ^ ((m & 4) ? P.Mm[2] : 0) ^ ((m & 8) ? P.Mm[3] : 0);
        const unsigned wb = ((wv & 1) ? P.Mw[0] : 0) ^ ((wv & 2) ? P.Mw[1] : 0)
                          ^ ((wv & 4) ? P.Mw[2] : 0) ^ ((wv & 8) ? P.Mw[3] : 0);
        const unsigned b0 = pm ^ wb;
        const f16x8 bf1 = *(const f16x8*)(Bf + (p * 64 + lane) * 16);
        const f16x8 bf2 = *(const f16x8*)(Bf + (p * 64 + lane) * 16 + 8);
        #pragma unroll
        for (int tt = 0; tt < 4; ++tt) {
            const unsigned s0 = b0 ^ ((tt & 1) ? P.Mt[0] : 0) ^ ((tt & 2) ? P.Mt[1] : 0);
            const unsigned sw = swzu(s0);
            const f16x8 av = *(const f16x8*)(S + plane_off + (sw ^ ((unsigned)(q & 1) << 3)));
            const f32x4 d1 = __builtin_amdgcn_mfma_f32_16x16x32_f16(av, bf1, z4, 0, 0, 0);
            const f32x4 d2 = __builtin_amdgcn_mfma_f32_16x16x32_f16(av, bf2, z4, 0, 0, 0);
            union { f16 h[4]; uint2 u; } c1, c2;
            #pragma unroll
            for (int r = 0; r < 4; ++r) { c1.h[r] = (f16)d1[r]; c2.h[r] = (f16)d2[r]; }
            const unsigned wu = sw ^ ((unsigned)q << 2);
            *(uint2*)(D + wu)       = c1.u;   // Re plane, b64
            *(uint2*)(D + NST + wu) = c2.u;   // Im plane, b64
        }
        __syncthreads();
    }

    // ---- <Z_0>: sign = parity(s & measR) over storage index s (state in buf0) ----
    float acc = 0.f;
    {
        const unsigned base = (unsigned)tid * 16;
        const unsigned swb  = swzu(base);
        const f16x8 r0 = *(const f16x8*)(Sh + swb);
        const f16x8 r1 = *(const f16x8*)(Sh + (swb ^ 8u));
        const f16x8 i0 = *(const f16x8*)(Sh + NST + swb);
        const f16x8 i1 = *(const f16x8*)(Sh + NST + (swb ^ 8u));
        const int pb = __popc(base & (unsigned)pl.measR) & 1;
        #pragma unroll
        for (int e = 0; e < 8; ++e) {
            float re = (float)r0[e], im = (float)i0[e];
            float pw = fmaf(re, re, im * im);
            acc += (pb ^ (__popc((unsigned)e & (unsigned)pl.measR) & 1)) ? -pw : pw;
            re = (float)r1[e]; im = (float)i1[e];
            pw = fmaf(re, re, im * im);
            acc += (pb ^ (__popc((unsigned)(e + 8) & (unsigned)pl.measR) & 1)) ? -pw : pw;
        }
    }
    #pragma unroll
    for (int off = 32; off > 0; off >>= 1) acc += __shfl_down(acc, off);
    if ((tid & 63) == 0) red[tid >> 6] = acc;
    __syncthreads();
    if (tid == 0) {
        float s = 0.f;
        #pragma unroll
        for (int i = 0; i < THREADS / 64; ++i) s += red[i];
        out[b] = s;
    }
}

// ---------------- host-side GF(2) layout scheduling ----------------
struct GFm { u16 col[14]; };   // col[b] = image of e_b

static unsigned ringp_host(unsigned x) {
    unsigned s = x;
    s ^= s >> 1; s ^= s >> 2; s ^= s >> 4; s ^= s >> 8;
    s &= 0x3FFFu;
    return (s ^ ((s & 1u) << 13)) & 0x3FFFu;
}
static u16 gf_apply(const GFm& m, u16 v) {
    u16 r = 0;
    for (int b = 0; b < 14; ++b) if ((v >> b) & 1) r ^= m.col[b];
    return r;
}
static GFm gf_compose(const GFm& A, const GFm& B) {   // A∘B
    GFm C;
    for (int b = 0; b < 14; ++b) C.col[b] = gf_apply(A, B.col[b]);
    return C;
}
static void rows_from(const GFm& A, u16 r[14]) {
    for (int i = 0; i < 14; ++i) {
        u16 mm = 0;
        for (int b = 0; b < 14; ++b) mm |= (u16)(((A.col[b] >> i) & 1) << b);
        r[i] = mm;
    }
}
static GFm from_rows(const u16 r[14]) {
    GFm A;
    for (int b = 0; b < 14; ++b) {
        u16 c = 0;
        for (int i = 0; i < 14; ++i) c |= (u16)(((r[i] >> b) & 1) << i);
        A.col[b] = c;
    }
    return A;
}
static GFm gf_inv(const GFm& A) {
    u16 M[14], I[14];
    rows_from(A, M);
    for (int i = 0; i < 14; ++i) I[i] = (u16)(1u << i);
    for (int c = 0; c < 14; ++c) {
        int p = c;
        while (p < 14 && !((M[p] >> c) & 1)) ++p;
        if (p == 14) continue;
        u16 t = M[c]; M[c] = M[p]; M[p] = t;
        t = I[c]; I[c] = I[p]; I[p] = t;
        for (int r2 = 0; r2 < 14; ++r2)
            if (r2 != c && ((M[r2] >> c) & 1)) { M[r2] ^= M[c]; I[r2] ^= I[c]; }
    }
    return from_rows(I);
}

static void build_plan(Plan& pl) {
    GFm ring, ringInv;
    for (int b = 0; b < 14; ++b) ring.col[b] = (u16)ringp_host(1u << b);
    ringInv = gf_inv(ring);

    // phi0: G0 bits {10..13}->slots[0..3]; G1 {6..9}->[4..7]; G2 {2..5}->[8..11]; b0->12, b1->13
    GFm phi;
    for (int j = 0; j < 4; ++j) phi.col[10 + j] = (u16)(1u << j);
    for (int j = 0; j < 4; ++j) phi.col[6 + j]  = (u16)(1u << (4 + j));
    for (int j = 0; j < 4; ++j) phi.col[2 + j]  = (u16)(1u << (8 + j));
    phi.col[0] = (u16)(1u << 12);
    phi.col[1] = (u16)(1u << 13);

    for (int b = 0; b < 14; ++b) pl.initM[b] = gf_apply(phi, ring.col[b]);

    const int gb[4][4] = {{10,11,12,13},{6,7,8,9},{2,3,4,5},{0,1,6,7}};

    for (int p = 0; p < NPASS; ++p) {
        const int g = p & 3;
        u16 uv[4];
        if (g < 3) for (int j = 0; j < 4; ++j) uv[j] = (u16)(1u << gb[g + 1][j]);
        else       for (int j = 0; j < 4; ++j) uv[j] = ringInv.col[10 + j];
        for (int j = 0; j < 4; ++j) pl.ps[p].Mm[j] = gf_apply(phi, uv[j]);

        u16 span[14]; int ns = 0;
        u16 tv[6]; int nt = 0;
        auto tryAdd = [&](u16 v) -> bool {
            bool ch = true;
            while (ch) {
                ch = false;
                for (int i = 0; i < ns; ++i) {
                    const int tb = 31 - __builtin_clz((unsigned)span[i]);
                    if ((v >> tb) & 1) { v ^= span[i]; ch = true; }
                }
            }
            if (!v) return false;
            span[ns++] = v;
            return true;
        };
        for (int j = 0; j < 4; ++j) tryAdd((u16)(1u << gb[g][j]));
        for (int j = 0; j < 4; ++j) tryAdd(uv[j]);
        for (int b2 = 0; b2 < 14 && nt < 6; ++b2)
            if (tryAdd((u16)(1u << b2))) tv[nt++] = (u16)(1u << b2);
        for (int i = 0; i < 2; ++i) pl.ps[p].Mt[i] = gf_apply(phi, tv[i]);
        for (int i = 0; i < 4; ++i) pl.ps[p].Mw[i] = gf_apply(phi, tv[i + 2]);

        GFm Bm;
        for (int j = 0; j < 4; ++j) Bm.col[j]     = (u16)(1u << gb[g][j]);
        for (int j = 0; j < 4; ++j) Bm.col[4 + j] = uv[j];
        for (int i = 0; i < 6; ++i) Bm.col[8 + i] = tv[i];
        GFm Binv = gf_inv(Bm);
        u16 img[14];
        for (int j = 0; j < 4; ++j) img[j]     = pl.ps[p].Mm[j];
        for (int j = 0; j < 4; ++j) img[4 + j] = (u16)(1u << j);
        for (int i = 0; i < 6; ++i) img[8 + i] = gf_apply(phi, tv[i]);
        GFm nphi;
        for (int b2 = 0; b2 < 14; ++b2) {
            const u16 coef = gf_apply(Binv, (u16)(1u << b2));
            u16 v = 0;
            for (int j = 0; j < 14; ++j) if ((coef >> j) & 1) v ^= img[j];
            nphi.col[b2] = v;
        }
        if (g == 3) nphi = gf_compose(nphi, ringInv);
        phi = nphi;
    }

    GFm pinv = gf_inv(phi);
    u16 rows[14];
    rows_from(pinv, rows);
    pl.measR = rows[13];
    pl._pad = 0;
}

extern "C" void kernel_launch(void* const* d_in, const int* in_sizes, int n_in,
                              void* d_out, int out_size, void* d_ws, size_t ws_size,
                              hipStream_t stream) {
    const float* x_raw  = (const float*)d_in[0];
    const float* angles = (const float*)d_in[1];
    float* out = (float*)d_out;
    const int bsz = in_sizes[0] / NW;

    Plan pl;
    build_plan(pl);

    const size_t lds = (size_t)4 * NST * sizeof(f16)          // 2x ping-pong state planes
                     + (size_t)NPASS * 64 * 16 * sizeof(f16)  // W B-fragments
                     + (size_t)4 * NW * 4 * sizeof(float2)    // fused gates
                     + (size_t)(THREADS / 64) * sizeof(float);
    (void)hipFuncSetAttribute((const void*)vqc_kernel,
                              hipFuncAttributeMaxDynamicSharedMemorySize, (int)lds);
    vqc_kernel<<<dim3(bsz), dim3(THREADS), lds, stream>>>(x_raw, angles, out, pl);
}